// Round 9
// baseline (37.587 us; speedup 1.0000x reference)
//
#include <hip/hip_runtime.h>
#include <math.h>

#define NN 128
#define MLINKS 256
#define HID 128
#define EF 17
#define BATCH 16
#define IN_DIM 86721
#define COMB 33089
#define NBLK2 259                  // ceil(33089/128)
#define PSTRIDE (NBLK2 * 128)      // 33152 floats: per-batch partial slab [p][h]

// input-row offsets
#define OFF_SD 0
#define OFF_SLOTS 256
#define OFF_SPEC 261
#define OFF_LF 321
#define OFF_BET 4673
#define OFF_ADJ 4801

__device__ __forceinline__ float fast_tanh(float x) {
    x = fminf(fmaxf(x, -15.f), 15.f);
    const float e = __expf(2.f * x);
    return (e - 1.f) / (e + 1.f);
}

__device__ __forceinline__ float wsum64(float v) {
    #pragma unroll
    for (int d = 1; d < 64; d <<= 1) v += __shfl_xor(v, d);
    return v;
}

// small-feature gather for ck in [0, 321)
__device__ __forceinline__ float gather_tail(const float* __restrict__ row, int ck) {
    if (ck < 256) return row[OFF_SD + ck];
    if (ck < 261) return row[OFF_SLOTS + ck - 256];
    if (ck < 291) { const int t = ck - 261; return row[OFF_SPEC + (t / 6) * 12 + (t % 6)]; }
    const int t = ck - 291; return row[OFF_SPEC + (t / 6) * 12 + 6 + (t % 6)];
}

// ---------------------------------------------------------------------------
// Kernel 1: fully fused front-end + split-K GEMM. 259 blocks x 1024 threads.
// Every block redundantly computes the per-batch scalars (cheap contraction:
// lf enters only via two dot products per batch), then synthesizes its own
// x-tile (rank-1 Hm for p<128; tails/alpha rows for p>=128) and runs the
// 4-way split-K GEMM vs W0 into part[b][p][h]. No xc intermediate, no k_pre.
// ---------------------------------------------------------------------------
__global__ __launch_bounds__(1024) void k_main(const float* __restrict__ in,
                                               const float* __restrict__ WH,
                                               const float* __restrict__ WE,
                                               const float* __restrict__ a_attn,
                                               const float* __restrict__ W0,
                                               float* __restrict__ part) {
    const int p = blockIdx.x;
    const int tid = threadIdx.x;
    const int wv = tid >> 6, lane = tid & 63;

    __shared__ float WH_s[HID];
    __shared__ float bet_s[BATCH][NN];        // 8 KB
    __shared__ float we3_s[EF];
    __shared__ float d12_s[2];
    __shared__ float se_s[BATCH], ec_s[BATCH], bs_s[BATCH];
    __shared__ float sab16[BATCH];
    __shared__ float xs[BATCH][128];          // 8 KB
    __shared__ float4 redA[3][256];           // 12 KB
    __shared__ float4 redB[3][256];

    // ---- stage: WH, betweenness (wave w = batch w), we3[e]=WE[e,:]·a3, d1, d2
    if (tid < HID) WH_s[tid] = WH[tid];
    {
        const float* bp = in + (size_t)wv * IN_DIM + OFF_BET;
        bet_s[wv][lane]      = bp[lane];
        bet_s[wv][lane + 64] = bp[lane + 64];
    }
    if (tid < EF * 32) {
        const int e = tid >> 5, c = tid & 31;
        float s = 0.f;
        #pragma unroll
        for (int h = c; h < HID; h += 32) s += WE[e * HID + h] * a_attn[2 * HID + h];
        #pragma unroll
        for (int d = 1; d < 32; d <<= 1) s += __shfl_xor(s, d);
        if (c == 0) we3_s[e] = s;
    }
    if (wv >= 14) {                            // d1 (wave 14), d2 (wave 15)
        const float* aa = a_attn + (wv - 14) * HID;
        float v = WH[lane] * aa[lane] + WH[lane + 64] * aa[lane + 64];
        v = wsum64(v);
        if (lane == 0) d12_s[wv - 14] = v;
    }
    __syncthreads();

    // ---- per-batch lf contraction: wave w = batch w.
    // se = (1/256) sum_{m,e} lf[m,e]*we3[e]; ec0 = (1/256) sum lf[m,e]*WE[e,0]
    {
        const float* lfb = in + (size_t)wv * IN_DIM + OFF_LF;
        const float we3v = (lane < EF) ? we3_s[lane] : 0.f;
        const float we0v = (lane < EF) ? WE[lane * HID] : 0.f;
        int e = lane % EF;                     // e of flat index 'lane'
        float sse = 0.f, sec = 0.f;
        #pragma unroll 4
        for (int j = 0; j < 68; ++j) {         // 68*64 = 4352 exactly
            const float v = lfb[lane + 64 * j];
            sse += v * __shfl(we3v, e);
            sec += v * __shfl(we0v, e);
            e += 13; if (e >= EF) e -= EF;     // (e + 64) mod 17
        }
        float bsum = bet_s[wv][lane] + bet_s[wv][lane + 64];
        sse = wsum64(sse); sec = wsum64(sec); bsum = wsum64(bsum);
        if (lane == 0) {
            se_s[wv] = sse * (1.0f / 256.0f);
            ec_s[wv] = sec * (1.0f / 256.0f);
            bs_s[wv] = bsum;
        }
    }
    __syncthreads();

    const float d1 = d12_s[0], d2 = d12_s[1];

    // ---- x-tile synthesis
    if (p < 128) {
        // wave w: softmax row p of batch w -> sab16[w]
        {
            const int b = wv;
            const float se = se_s[b], ec0 = ec_s[b];
            const float* row = in + (size_t)b * IN_DIM;
            const float betA = bet_s[b][lane], betB = bet_s[b][lane + 64];
            const float sq = bet_s[b][p] * d1 + se;
            const float adj1 = row[OFF_ADJ + p * NN + lane];
            const float adj2 = row[OFF_ADJ + p * NN + 64 + lane];
            float e1 = (adj1 > 0.f) ? __expf(fast_tanh(sq + betA * d2)) : 0.f;
            float e2 = (adj2 > 0.f) ? __expf(fast_tanh(sq + betB * d2)) : 0.f;
            float s  = wsum64(e1 + e2);
            float sb = wsum64(e1 * betA + e2 * betB);
            if (lane == 0)
                sab16[b] = (s > 0.f) ? (ec0 * sb / s)
                                     : (ec0 * bs_s[b] * (1.0f / 128.0f));
        }
        __syncthreads();
        for (int idx = tid; idx < BATCH * 128; idx += 1024) {
            const int bb = idx >> 7, kk = idx & 127;
            xs[bb][kk] = sab16[bb] * WH_s[kk];
        }
    } else {
        const int base = p * 128 - 16705;      // alpha flat index at kk=0 (signed)

        if (p == NBLK2 - 1) {                  // zero-pad beyond COMB
            for (int i = tid; i < BATCH * 128; i += 1024) xs[i >> 7][i & 127] = 0.f;
            __syncthreads();
        }
        if (p <= 130) {                        // SD/slots/bands portion
            const int ck0 = p * 128 - 16384;
            for (int i = tid; i < BATCH * 128; i += 1024) {
                const int b = i >> 7, kk = i & 127, ck = ck0 + kk;
                if (ck < 321)
                    xs[b][kk] = gather_tail(in + (size_t)b * IN_DIM, ck);
            }
        }
        // alpha rows straddled by this K-window
        const int a_lo = (base > 0) ? base : 0;
        const int a_hi = (base + 128 < 16384) ? base + 128 : 16384;  // exclusive
        if (a_lo < a_hi) {
            const int r_lo = a_lo >> 7;
            const int r_hi = (a_hi - 1) >> 7;
            const int ntasks = (r_hi - r_lo + 1) * 16;
            for (int t = wv; t < ntasks; t += 16) {
                const int b = t & 15, i = r_lo + (t >> 4);
                const float se = se_s[b];
                const float* row = in + (size_t)b * IN_DIM;
                const float betA = bet_s[b][lane], betB = bet_s[b][lane + 64];
                const float sq = bet_s[b][i] * d1 + se;
                const float adj1 = row[OFF_ADJ + i * NN + lane];
                const float adj2 = row[OFF_ADJ + i * NN + 64 + lane];
                float e1 = (adj1 > 0.f) ? __expf(fast_tanh(sq + betA * d2)) : 0.f;
                float e2 = (adj2 > 0.f) ? __expf(fast_tanh(sq + betB * d2)) : 0.f;
                const float s = wsum64(e1 + e2);
                float inv;
                if (s > 0.f) inv = 1.0f / s;
                else { e1 = 1.f; e2 = 1.f; inv = 1.0f / 128.0f; }
                const int kk1 = i * 128 + lane - base;
                const int kk2 = kk1 + 64;
                if (kk1 >= 0 && kk1 < 128) xs[b][kk1] = e1 * inv;
                if (kk2 >= 0 && kk2 < 128) xs[b][kk2] = e2 * inv;
            }
        }
    }
    __syncthreads();

    // ---- split-K GEMM: part[:, p, :] = xs @ W0[p*128 : p*128+128, :]
    const int kq  = tid >> 8;        // 0..3: k quarter
    const int sub = tid & 255;
    const int g = sub >> 5;          // 0..7 -> batches 2g, 2g+1
    const int c = sub & 31;          // float4 column group
    float4 acc0 = {0.f, 0.f, 0.f, 0.f};
    float4 acc1 = {0.f, 0.f, 0.f, 0.f};
    const float4* __restrict__ W0v =
        reinterpret_cast<const float4*>(W0 + (size_t)p * 128 * HID);

    if (p != NBLK2 - 1) {
        #pragma unroll 16
        for (int j = 0; j < 32; ++j) {
            const int kk = kq * 32 + j;
            const float4 w = W0v[kk * 32 + c];
            const float xa = xs[2 * g][kk];
            const float xb = xs[2 * g + 1][kk];
            acc0.x += xa * w.x; acc0.y += xa * w.y; acc0.z += xa * w.z; acc0.w += xa * w.w;
            acc1.x += xb * w.x; acc1.y += xb * w.y; acc1.z += xb * w.z; acc1.w += xb * w.w;
        }
    } else {
        const int klen = COMB - (NBLK2 - 1) * 128;   // 65
        const int kend = (kq * 32 + 32 < klen) ? kq * 32 + 32 : klen;
        for (int kk = kq * 32; kk < kend; ++kk) {
            const float4 w = W0v[kk * 32 + c];
            const float xa = xs[2 * g][kk];
            const float xb = xs[2 * g + 1][kk];
            acc0.x += xa * w.x; acc0.y += xa * w.y; acc0.z += xa * w.z; acc0.w += xa * w.w;
            acc1.x += xb * w.x; acc1.y += xb * w.y; acc1.z += xb * w.z; acc1.w += xb * w.w;
        }
    }

    if (kq > 0) { redA[kq - 1][sub] = acc0; redB[kq - 1][sub] = acc1; }
    __syncthreads();
    if (kq == 0) {
        #pragma unroll
        for (int t = 0; t < 3; ++t) {
            const float4 oA = redA[t][sub], oB = redB[t][sub];
            acc0.x += oA.x; acc0.y += oA.y; acc0.z += oA.z; acc0.w += oA.w;
            acc1.x += oB.x; acc1.y += oB.y; acc1.z += oB.z; acc1.w += oB.w;
        }
        float4* pA = reinterpret_cast<float4*>(part + (size_t)(2 * g) * PSTRIDE + p * 128);
        float4* pB = reinterpret_cast<float4*>(part + (size_t)(2 * g + 1) * PSTRIDE + p * 128);
        pA[c] = acc0;
        pB[c] = acc1;
    }
}

// ---------------------------------------------------------------------------
// Kernel 2: fused partial-reduce + 4-layer ReLU MLP, batch-parallel.
// 16 blocks x 1024 threads (8 p-groups x 128 h). Contiguous per-batch slab.
// ---------------------------------------------------------------------------
__global__ __launch_bounds__(1024) void k_tail(const float* __restrict__ part,
                                               const float* __restrict__ b0,
                                               const float* __restrict__ Wr,
                                               const float* __restrict__ br,
                                               float* __restrict__ out) {
    const int b = blockIdx.x;
    const int tid = threadIdx.x;
    const int h = tid & 127;
    const int q = tid >> 7;            // 0..7

    __shared__ float xs[2][HID];
    __shared__ float red[8][HID];

    {
        const float* pb = part + (size_t)b * PSTRIDE + h;
        float s = 0.f;
        #pragma unroll 16
        for (int j = 0; j < 32; ++j)
            s += pb[(size_t)(q * 32 + j) * 128];
        if (q < 3) s += pb[(size_t)(256 + q) * 128];
        red[q][h] = s;
    }
    __syncthreads();
    if (q == 0) {
        float t = ((red[0][h] + red[1][h]) + (red[2][h] + red[3][h]))
                + ((red[4][h] + red[5][h]) + (red[6][h] + red[7][h])) + b0[h];
        xs[0][h] = fmaxf(t, 0.f);
    }
    __syncthreads();

    int cur = 0;
    for (int L = 0; L < 4; ++L) {
        const float* __restrict__ W = Wr + (size_t)L * HID * HID;
        float acc = 0.f;
        #pragma unroll
        for (int j = 0; j < 16; ++j) {
            const int k = q * 16 + j;
            acc += xs[cur][k] * W[k * HID + h];
        }
        red[q][h] = acc;
        __syncthreads();
        if (q == 0) {
            float t = ((red[0][h] + red[1][h]) + (red[2][h] + red[3][h]))
                    + ((red[4][h] + red[5][h]) + (red[6][h] + red[7][h]))
                    + br[L * HID + h];
            xs[cur ^ 1][h] = fmaxf(t, 0.f);
        }
        cur ^= 1;
        __syncthreads();
    }
    if (tid < HID) out[b * HID + tid] = xs[cur][tid];
}

// ---------------------------------------------------------------------------
extern "C" void kernel_launch(void* const* d_in, const int* in_sizes, int n_in,
                              void* d_out, int out_size, void* d_ws, size_t ws_size,
                              hipStream_t stream) {
    const float* in     = (const float*)d_in[0];
    const float* WH     = (const float*)d_in[1];
    const float* WE     = (const float*)d_in[2];
    const float* a_attn = (const float*)d_in[3];
    const float* W0     = (const float*)d_in[4];
    const float* b0     = (const float*)d_in[5];
    const float* Wr     = (const float*)d_in[6];
    const float* br     = (const float*)d_in[7];
    float* out = (float*)d_out;

    float* part = (float*)d_ws;                // 16 * 33152 floats

    hipLaunchKernelGGL(k_main, dim3(NBLK2), dim3(1024), 0, stream,
                       in, WH, WE, a_attn, W0, part);
    hipLaunchKernelGGL(k_tail, dim3(BATCH), dim3(1024), 0, stream,
                       part, b0, Wr, br, out);
}